// Round 10
// baseline (1941.639 us; speedup 1.0000x reference)
//
#include <hip/hip_runtime.h>
#include <math.h>

#define BN_SC 0.9999950000375f
#define P2N   (6.283185307179586f / 126.f)
#define ATT_SCALE 0.35355339059327373f

typedef float v4f __attribute__((ext_vector_type(4)));

enum { M_LOCAL = 0, M_GABOR = 1, M_BNRELU6 = 2, M_BIASRELU = 3 };

// ---------------- weight prep: fold BN scale into w_l1 / w_l2 ----------------
__global__ __launch_bounds__(256) void prep_k(
    const float* __restrict__ w_l1, const float* __restrict__ g_l1, const float* __restrict__ b_l1,
    const float* __restrict__ w_l2, const float* __restrict__ g_l2, const float* __restrict__ b_l2,
    float* __restrict__ w1s, float* __restrict__ w2s, float* __restrict__ bs)
{
  int i = blockIdx.x * 256 + threadIdx.x;
  if (i < 36864) w1s[i] = w_l1[i] * (g_l1[i / 576] * BN_SC);
  if (i < 4096)  w2s[i] = w_l2[i] * (g_l2[i / 64] * BN_SC);
  if (i < 64)    bs[i]  = b_l1[i] + b_l2[i];
}

// ------------- rpb bias pre-gather: rpbt[h][j*64+i] = rpb[relidx[i*64+j]*8+h] -------------
__global__ __launch_bounds__(256) void rpbprep_k(
    const float* __restrict__ rpb, const int* __restrict__ relidx, float* __restrict__ rpbt)
{
  int idx = blockIdx.x * 256 + threadIdx.x; // 32768
  int h = idx >> 12, r = idx & 4095, j = r >> 6, i = r & 63;
  rpbt[idx] = rpb[relidx[i * 64 + j] * 8 + h];
}

// -------- fp32 register-tiled conv3x3, STREAMED per-chunk weights (13.2 KB LDS) --------
// block 256 thr: tx[0,8) x 4px, ty[0,8) x 2px, tc[0,4) x 4cout -> tile 32x16 px, 16 couts.
// grid (32, B, 4). Per 4-cin chunk: stage 18x34 activation tile (pitch 37) + wt[4][9][16]
// (2.3 KB, L2-broadcast across blocks). Occupancy cap moves from LDS (was 51.7KB/3 blk/CU)
// to VGPR (~88 -> 4 waves/SIMD, ~50%). Numerics identical to R9's conv3x3r_k.
template<int MODE, int IN_HW, int OUT_HW, int PAD>
__global__ __launch_bounds__(256)
void conv3x3s_k(const float* __restrict__ in, const float* __restrict__ wa,
                const float* __restrict__ wb, const float* __restrict__ pa,
                const float* __restrict__ pb, float* __restrict__ out)
{
  __shared__ float wt[4 * 9 * 16];      // [ci][tap][co16]  2304 B
  __shared__ float w1c[4 * 16];         // [ci][co16] (LOCAL 1x1)  256 B
  __shared__ float tile[4 * 18 * 37];   // 4 cin x 18 rows x pitch 37  10656 B
  const int tid = threadIdx.x;
  const int tx = tid & 7, ty = (tid >> 3) & 7, tc = tid >> 6;
  const int bx = blockIdx.x & 3, by = blockIdx.x >> 2;
  const int b = blockIdx.y, cg = blockIdx.z;
  const int x0 = bx * 32, y0 = by * 16;
  const int ix0 = x0 - PAD, iy0 = y0 - PAD;
  const float* inb = in + (size_t)b * 64 * IN_HW * IN_HW;

  float acc[4][2][4];
#pragma unroll
  for (int a = 0; a < 4; ++a)
#pragma unroll
    for (int py = 0; py < 2; ++py)
#pragma unroll
      for (int px = 0; px < 4; ++px) acc[a][py][px] = 0.f;

  const int yb = ty * 2, xb = tx * 4;

  for (int cc = 0; cc < 64; cc += 4) {
    __syncthreads();
    // ---- stage activation tile ----
    for (int e = tid; e < 4 * 18 * 34; e += 256) {
      int ci = e / 612, r = e - ci * 612;
      int row = r / 34, col = r - row * 34;
      int iy = iy0 + row, ix = ix0 + col;
      float v = 0.f;
      if ((unsigned)iy < (unsigned)IN_HW && (unsigned)ix < (unsigned)IN_HW)
        v = inb[((size_t)(cc + ci) * IN_HW + iy) * IN_HW + ix];
      tile[ci * 666 + row * 37 + col] = v;
    }
    // ---- stage this chunk's weights (2.3 KB) ----
    for (int e = tid; e < 576; e += 256) {
      int co = e & 15, q = e >> 4;       // q = ci*9+o in [0,36)
      int o = q % 9, ci = q / 9;
      int c = cg * 16 + co;
      int cin = cc + ci;
      float v;
      if (MODE == M_GABOR)
        v = (c < 32) ? wa[((size_t)c * 64 + cin) * 9 + o]
                     : wb[((size_t)(c - 32) * 64 + cin) * 9 + o];
      else
        v = wa[((size_t)c * 64 + cin) * 9 + o];
      wt[q * 16 + co] = v;
    }
    if (MODE == M_LOCAL && tid < 64) {
      int co = tid & 15, ci = tid >> 4;
      w1c[ci * 16 + co] = wb[(size_t)(cg * 16 + co) * 64 + cc + ci];
    }
    __syncthreads();
#pragma unroll
    for (int ci = 0; ci < 4; ++ci) {
      float p[4][6];
#pragma unroll
      for (int r = 0; r < 4; ++r)
#pragma unroll
        for (int c2 = 0; c2 < 6; ++c2)
          p[r][c2] = tile[ci * 666 + (yb + r) * 37 + xb + c2];
      v4f wv[9];
#pragma unroll
      for (int o = 0; o < 9; ++o)
        wv[o] = *(const v4f*)&wt[(ci * 9 + o) * 16 + tc * 4];
#pragma unroll
      for (int dy = 0; dy < 3; ++dy)
#pragma unroll
        for (int dx = 0; dx < 3; ++dx) {
          v4f w = wv[dy * 3 + dx];
#pragma unroll
          for (int a = 0; a < 4; ++a) {
            float wc = w[a];
#pragma unroll
            for (int py = 0; py < 2; ++py)
#pragma unroll
              for (int px = 0; px < 4; ++px)
                acc[a][py][px] += p[py + dy][px + dx] * wc;
          }
        }
      if (MODE == M_LOCAL) {
        v4f w1 = *(const v4f*)&w1c[ci * 16 + tc * 4];
#pragma unroll
        for (int a = 0; a < 4; ++a) {
          float wc = w1[a];
#pragma unroll
          for (int py = 0; py < 2; ++py)
#pragma unroll
            for (int px = 0; px < 4; ++px)
              acc[a][py][px] += p[py + 1][px + 1] * wc;
        }
      }
    }
  }

#pragma unroll
  for (int a = 0; a < 4; ++a) {
    const int c = cg * 16 + tc * 4 + a;
    float scale = 1.f, bias;
    if (MODE == M_LOCAL)        { bias = pa[c]; }
    else if (MODE == M_GABOR)   { bias = (c < 32) ? pa[c] : pb[c - 32]; }
    else if (MODE == M_BNRELU6) { scale = pa[c] * BN_SC; bias = pb[c]; }
    else                        { bias = pa[c]; }
#pragma unroll
    for (int py = 0; py < 2; ++py) {
      int oy = y0 + yb + py;
      if (oy >= OUT_HW) continue;
      float* op = out + (((size_t)b * 64 + c) * OUT_HW + oy) * OUT_HW;
      int ox0 = x0 + xb;
#pragma unroll
      for (int px = 0; px < 4; ++px) {
        if (ox0 + px >= OUT_HW) continue;
        float r = acc[a][py][px] * scale + bias;
        if (MODE == M_BNRELU6) r = fminf(fmaxf(r, 0.f), 6.f);
        if (MODE == M_BIASRELU) r = fmaxf(r, 0.f);
        op[ox0 + px] = r;
      }
    }
  }
}

// -------- fp32 register-tiled stride-2 conv3x3 valid (125 -> 62), + bias + relu --------
__global__ __launch_bounds__(256)
void convgc_t(const float* __restrict__ in, const float* __restrict__ w,
              const float* __restrict__ bias, float* __restrict__ out)
{
  __shared__ float tile[4 * 33 * 35];
  __shared__ float wt[4 * 9 * 32];
  const int tid = threadIdx.x;
  const int tx = tid & 7, ty = (tid >> 3) & 7, tc = tid >> 6;
  const int bx = blockIdx.x & 3, by = blockIdx.x >> 2;
  const int b = blockIdx.y, zg = blockIdx.z;
  const int x0 = bx * 16, y0 = by * 16;
  const float* inb = in + (size_t)b * 64 * 125 * 125;

  float acc[8][2][2];
#pragma unroll
  for (int a = 0; a < 8; ++a)
#pragma unroll
    for (int py = 0; py < 2; ++py)
#pragma unroll
      for (int px = 0; px < 2; ++px) acc[a][py][px] = 0.f;

  for (int cc = 0; cc < 64; cc += 4) {
    __syncthreads();
    for (int e = tid; e < 4 * 33 * 33; e += 256) {
      int ci = e / 1089, r = e - ci * 1089;
      int row = r / 33, col = r - row * 33;
      int iy = 2 * y0 + row, ix = 2 * x0 + col;
      float v = 0.f;
      if (iy < 125 && ix < 125)
        v = inb[((size_t)(cc + ci) * 125 + iy) * 125 + ix];
      tile[ci * 1155 + row * 35 + col] = v;
    }
    for (int e = tid; e < 1152; e += 256) {
      int co = e & 31, q = e >> 5;
      int ci = q / 9, o = q - ci * 9;
      wt[q * 32 + co] = w[((size_t)(zg * 32 + co) * 64 + cc + ci) * 9 + o];
    }
    __syncthreads();
#pragma unroll
    for (int ci = 0; ci < 4; ++ci) {
      float p[5][5];
#pragma unroll
      for (int r = 0; r < 5; ++r)
#pragma unroll
        for (int c2 = 0; c2 < 5; ++c2)
          p[r][c2] = tile[ci * 1155 + (4 * ty + r) * 35 + 4 * tx + c2];
#pragma unroll
      for (int o = 0; o < 9; ++o) {
        const int dy = o / 3, dx = o - dy * 3;
        v4f w0 = *(const v4f*)&wt[(ci * 9 + o) * 32 + tc * 8];
        v4f w1 = *(const v4f*)&wt[(ci * 9 + o) * 32 + tc * 8 + 4];
#pragma unroll
        for (int py = 0; py < 2; ++py)
#pragma unroll
          for (int px = 0; px < 2; ++px) {
            float pv = p[2 * py + dy][2 * px + dx];
#pragma unroll
            for (int a = 0; a < 4; ++a) {
              acc[a][py][px]     += pv * w0[a];
              acc[a + 4][py][px] += pv * w1[a];
            }
          }
      }
    }
  }

#pragma unroll
  for (int a = 0; a < 8; ++a) {
    const int c = zg * 32 + tc * 8 + a;
    const float bv = bias[c];
#pragma unroll
    for (int py = 0; py < 2; ++py) {
      int oy = y0 + ty * 2 + py;
      if (oy >= 62) continue;
      float* op = out + (((size_t)b * 64 + c) * 62 + oy) * 62;
#pragma unroll
      for (int px = 0; px < 2; ++px) {
        int ox = x0 + tx * 2 + px;
        if (ox >= 62) continue;
        op[ox] = fmaxf(acc[a][py][px] + bv, 0.f);
      }
    }
  }
}

// ======================= DFT (126-pt), table-based, Hermitian-half =======================

__global__ __launch_bounds__(64)
void dft_rows_fwd_k(const float* __restrict__ in, float* __restrict__ outC, int planeBase)
{
  __shared__ float2 r2[63];
  __shared__ float2 T[126];
  const int lp = blockIdx.x / 126, n1 = blockIdx.x % 126;
  const int tid = threadIdx.x;
  const float2* row = (const float2*)(in + (size_t)(planeBase + lp) * 15876 + (size_t)n1 * 126);
  if (tid < 63) r2[tid] = row[tid];
  for (int e = tid; e < 126; e += 64) { float s, c; sincosf(P2N * (float)e, &s, &c); T[e] = make_float2(c, s); }
  __syncthreads();
  const int k2 = tid;
  const int inc = (2 * k2) % 126;
  int m = 0;
  float Er = 0.f, Ei = 0.f, Or = 0.f, Oi = 0.f;
  for (int n = 0; n < 63; ++n) {
    float2 rv = r2[n];
    float2 t = T[m];
    Er += rv.x * t.x; Ei -= rv.x * t.y;
    Or += rv.y * t.x; Oi -= rv.y * t.y;
    m += inc; if (m >= 126) m -= 126;
  }
  float c = T[k2].x, s = T[k2].y;
  float2* o = (float2*)(outC + (size_t)lp * 16128 + (size_t)n1 * 128);
  o[k2] = make_float2(Er + c * Or + s * Oi, Ei + c * Oi - s * Or);
}

__global__ __launch_bounds__(256)
void dft_cols_fwd_mask_k(const float* __restrict__ inC, float* __restrict__ outC)
{
  __shared__ float2 S[4032];
  __shared__ float2 T[126];
  const int lp = blockIdx.x >> 1, gbase = (blockIdx.x & 1) * 32;
  const int tid = threadIdx.x;
  if (tid < 126) { float s, c; sincosf(P2N * (float)tid, &s, &c); T[tid] = make_float2(c, s); }
  const float2* src = (const float2*)(inC + (size_t)lp * 16128);
  for (int e = tid; e < 4032; e += 256) {
    int n1 = e >> 5, c = e & 31;
    S[e] = src[n1 * 64 + gbase + c];
  }
  __syncthreads();
  float2* dst = (float2*)(outC + (size_t)lp * 16128);
  for (int e = tid; e < 2016; e += 256) {
    int k1 = e >> 5, c = e & 31;
    int k2 = gbase + c;
    int inc = 2 * k1;
    int me = 0, mo = k1;
    float Er = 0.f, Ei = 0.f, Or = 0.f, Oi = 0.f;
    for (int u = 0; u < 63; ++u) {
      float2 s0 = S[(2 * u) * 32 + c];
      float2 t0 = T[me];
      Er += s0.x * t0.x + s0.y * t0.y;
      Ei += s0.y * t0.x - s0.x * t0.y;
      float2 s1 = S[(2 * u + 1) * 32 + c];
      float2 t1 = T[mo];
      Or += s1.x * t1.x + s1.y * t1.y;
      Oi += s1.y * t1.x - s1.x * t1.y;
      me += inc; if (me >= 126) me -= 126;
      mo += inc; if (mo >= 126) mo -= 126;
    }
    int f2 = (k2 <= 62) ? k2 : k2 - 126;
    float ar = Er + Or, ai = Ei + Oi;
    float br = Er - Or, bi = Ei - Oi;
    float sa = (k1 * k1 + f2 * f2 > 1600) ? sqrtf(ar * ar + ai * ai) * (1.f / 15876.f) : 0.f;
    int f1b = k1 - 63;
    float sb = (f1b * f1b + f2 * f2 > 1600) ? sqrtf(br * br + bi * bi) * (1.f / 15876.f) : 0.f;
    dst[(size_t)k1 * 64 + k2]        = make_float2(ar * sa, ai * sa);
    dst[(size_t)(k1 + 63) * 64 + k2] = make_float2(br * sb, bi * sb);
  }
}

__global__ __launch_bounds__(256)
void dft_cols_inv_k(const float* __restrict__ inC, float* __restrict__ outC)
{
  __shared__ float2 S[4032];
  __shared__ float2 T[126];
  const int lp = blockIdx.x >> 1, gbase = (blockIdx.x & 1) * 32;
  const int tid = threadIdx.x;
  if (tid < 126) { float s, c; sincosf(P2N * (float)tid, &s, &c); T[tid] = make_float2(c, s); }
  const float2* src = (const float2*)(inC + (size_t)lp * 16128);
  for (int e = tid; e < 4032; e += 256) {
    int k1 = e >> 5, c = e & 31;
    S[e] = src[k1 * 64 + gbase + c];
  }
  __syncthreads();
  float2* dst = (float2*)(outC + (size_t)lp * 16128);
  for (int e = tid; e < 2016; e += 256) {
    int n1 = e >> 5, c = e & 31;
    int k2 = gbase + c;
    int inc = (2 * n1) % 126;
    int me = 0, mo = n1;
    float Er = 0.f, Ei = 0.f, Or = 0.f, Oi = 0.f;
    for (int u = 0; u < 63; ++u) {
      float2 s0 = S[(2 * u) * 32 + c];
      float2 t0 = T[me];
      Er += s0.x * t0.x - s0.y * t0.y;
      Ei += s0.x * t0.y + s0.y * t0.x;
      float2 s1 = S[(2 * u + 1) * 32 + c];
      float2 t1 = T[mo];
      Or += s1.x * t1.x - s1.y * t1.y;
      Oi += s1.x * t1.y + s1.y * t1.x;
      me += inc; if (me >= 126) me -= 126;
      mo += inc; if (mo >= 126) mo -= 126;
    }
    dst[(size_t)n1 * 64 + k2]        = make_float2(Er + Or, Ei + Oi);
    dst[(size_t)(n1 + 63) * 64 + k2] = make_float2(Er - Or, Ei - Oi);
  }
}

__global__ __launch_bounds__(128)
void dft_rows_inv_mix_k(const float* __restrict__ inC, const float* __restrict__ xc0,
                        const float* __restrict__ gb_w, float* __restrict__ out, int planeBase)
{
  __shared__ float2 Z[64];
  __shared__ float2 T[126];
  const int lp = blockIdx.x / 126, n1 = blockIdx.x % 126;
  const int tid = threadIdx.x;
  const float2* src = (const float2*)(inC + (size_t)lp * 16128 + (size_t)n1 * 128);
  if (tid < 64) Z[tid] = src[tid];
  if (tid < 126) { float s, c; sincosf(P2N * (float)tid, &s, &c); T[tid] = make_float2(c, s); }
  __syncthreads();
  const int n2 = tid;
  if (n2 < 126) {
    float a = Z[0].x + ((n2 & 1) ? -Z[63].x : Z[63].x);
    float acc = 0.f;
    int m = n2;
    for (int k2 = 1; k2 < 63; ++k2) {
      float2 z = Z[k2];
      float2 t = T[m];
      acc += z.x * t.x - z.y * t.y;
      m += n2; if (m >= 126) m -= 126;
    }
    a += 2.f * acc;
    float w0 = fmaxf(gb_w[0], 0.f), w1 = fmaxf(gb_w[1], 0.f);
    float inv = 1.f / (w0 + w1 + 1e-8f);
    size_t gi = (size_t)(planeBase + lp) * 15876 + (size_t)n1 * 126 + n2;
    out[gi] = (w0 * inv) * fabsf(a) + (w1 * inv) * xc0[gi];
  }
}

// ---------------- maxpool 2x2 stride1: 126 -> 125 ----------------
__global__ __launch_bounds__(256) void mp1_k(const float* __restrict__ in, float* __restrict__ out)
{
  int idx = blockIdx.x * 256 + threadIdx.x;
  if (idx >= 512 * 125 * 125) return;
  int x = idx % 125, y = (idx / 125) % 125, p = idx / 15625;
  const float* ip = in + (size_t)p * 15876 + (size_t)y * 126 + x;
  out[idx] = fmaxf(fmaxf(ip[0], ip[1]), fmaxf(ip[126], ip[127]));
}

// ---------------- maxpool 2x2 stride2: 62 -> 31 ----------------
__global__ __launch_bounds__(256) void mp2_k(const float* __restrict__ in, float* __restrict__ out)
{
  int idx = blockIdx.x * 256 + threadIdx.x;
  if (idx >= 512 * 31 * 31) return;
  int x = idx % 31, y = (idx / 31) % 31, p = idx / 961;
  const float* ip = in + (size_t)p * 3844 + (size_t)(2 * y) * 62 + 2 * x;
  out[idx] = fmaxf(fmaxf(ip[0], ip[1]), fmaxf(ip[62], ip[63]));
}

// ---------------- bilinear resize 31 -> 128 ----------------
__global__ __launch_bounds__(256) void resize_k(const float* __restrict__ in, float* __restrict__ out)
{
  int idx = blockIdx.x * 256 + threadIdx.x;
  if (idx >= 512 * 128 * 128) return;
  int x = idx & 127, y = (idx >> 7) & 127, p = idx >> 14;
  float sy = (y + 0.5f) * (31.f / 128.f) - 0.5f; sy = fminf(fmaxf(sy, 0.f), 30.f);
  float sx = (x + 0.5f) * (31.f / 128.f) - 0.5f; sx = fminf(fmaxf(sx, 0.f), 30.f);
  int y0 = (int)sy; float fy = sy - (float)y0; int y1 = min(y0 + 1, 30);
  int x0 = (int)sx; float fx = sx - (float)x0; int x1 = min(x0 + 1, 30);
  const float* ip = in + (size_t)p * 961;
  float v = (1.f - fy) * ((1.f - fx) * ip[y0 * 31 + x0] + fx * ip[y0 * 31 + x1])
          + fy         * ((1.f - fx) * ip[y1 * 31 + x0] + fx * ip[y1 * 31 + x1]);
  out[idx] = v;
}

// ---------------- 1x1 conv (w_gc2 + bias) + log_softmax over 64 channels ----------------
__global__ __launch_bounds__(256)
void pwlsm_k(const float* __restrict__ in, const float* __restrict__ w,
             const float* __restrict__ bias, float* __restrict__ out)
{
  __shared__ float zs[64 * 256];
  int idx = blockIdx.x * 256 + threadIdx.x;
  int b = idx >> 14, px = idx & 16383;
  const float* ip = in + ((size_t)b << 20) + px;
  float v[64];
#pragma unroll
  for (int i = 0; i < 64; ++i) v[i] = ip[(size_t)i << 14];
  float m = -1e30f;
  for (int co = 0; co < 64; ++co) {
    float s = bias[co];
    const float* wk = w + co * 64;
#pragma unroll
    for (int i = 0; i < 64; ++i) s += v[i] * wk[i];
    zs[co * 256 + threadIdx.x] = s;
    m = fmaxf(m, s);
  }
  float sum = 0.f;
  for (int co = 0; co < 64; ++co) sum += __expf(zs[co * 256 + threadIdx.x] - m);
  float lse = m + __logf(sum);
  float* op = out + ((size_t)b << 20) + px;
  for (int co = 0; co < 64; ++co) op[(size_t)co << 14] = zs[co * 256 + threadIdx.x] - lse;
}

// ---------------- windowed attention: wave-per-head, register softmax ----------------
__global__ __launch_bounds__(256)
void attn_w_k(const float* __restrict__ x, const float* __restrict__ wqkv,
              const float* __restrict__ rpbt, float* __restrict__ o_out)
{
  __shared__ float xt[4096];
  __shared__ float kvb[4][2][64][8];
  const int tid = threadIdx.x;
  const int lane = tid & 63;
  const int wv = __builtin_amdgcn_readfirstlane(tid >> 6);
  const int b = blockIdx.x >> 8, gy = (blockIdx.x >> 4) & 15, gx = blockIdx.x & 15;
  const int y0 = gy * 8, x0 = gx * 8;

  for (int e = tid; e < 4096; e += 256) {
    int cin = e >> 6, pix = e & 63;
    xt[e] = x[((size_t)(b * 64 + cin) * 128 + (y0 + (pix >> 3))) * 128 + x0 + (pix & 7)];
  }
  __syncthreads();

  const int row = y0 + (lane >> 3), col = x0 + (lane & 7);

  for (int hh = 0; hh < 2; ++hh) {
    const int h = hh * 4 + wv;
    const float* wq = wqkv + (size_t)(h * 8) * 64;
    const float* wk = wqkv + (size_t)(64 + h * 8) * 64;
    const float* wvv = wqkv + (size_t)(128 + h * 8) * 64;
    float q[8], kk[8], vv[8];
#pragma unroll
    for (int d = 0; d < 8; ++d) { q[d] = 0.f; kk[d] = 0.f; vv[d] = 0.f; }
    for (int cb = 0; cb < 64; cb += 4) {
      float xv0 = xt[(cb + 0) * 64 + lane];
      float xv1 = xt[(cb + 1) * 64 + lane];
      float xv2 = xt[(cb + 2) * 64 + lane];
      float xv3 = xt[(cb + 3) * 64 + lane];
#pragma unroll
      for (int d = 0; d < 8; ++d) {
        float4 a = *(const float4*)(wq + d * 64 + cb);
        q[d] += xv0 * a.x + xv1 * a.y + xv2 * a.z + xv3 * a.w;
        float4 bq = *(const float4*)(wk + d * 64 + cb);
        kk[d] += xv0 * bq.x + xv1 * bq.y + xv2 * bq.z + xv3 * bq.w;
        float4 cq = *(const float4*)(wvv + d * 64 + cb);
        vv[d] += xv0 * cq.x + xv1 * cq.y + xv2 * cq.z + xv3 * cq.w;
      }
    }
#pragma unroll
    for (int d = 0; d < 8; ++d) {
      kvb[wv][0][lane][d] = kk[d];
      kvb[wv][1][lane][d] = vv[d];
    }
    __syncthreads();

    const float* rb = rpbt + h * 4096;
    float P[64];
    float m = -1e30f;
#pragma unroll
    for (int j = 0; j < 64; ++j) {
      float4 k0 = *(const float4*)&kvb[wv][0][j][0];
      float4 k1 = *(const float4*)&kvb[wv][0][j][4];
      float s = q[0] * k0.x + q[1] * k0.y + q[2] * k0.z + q[3] * k0.w
              + q[4] * k1.x + q[5] * k1.y + q[6] * k1.z + q[7] * k1.w;
      s = s * ATT_SCALE + rb[j * 64 + lane];
      P[j] = s;
      m = fmaxf(m, s);
    }
    float sum = 0.f;
#pragma unroll
    for (int j = 0; j < 64; ++j) { float p = __expf(P[j] - m); P[j] = p; sum += p; }
    float inv = 1.f / sum;

    float acc[8];
#pragma unroll
    for (int d = 0; d < 8; ++d) acc[d] = 0.f;
#pragma unroll
    for (int j = 0; j < 64; ++j) {
      float p = P[j];
      float4 v0 = *(const float4*)&kvb[wv][1][j][0];
      float4 v1 = *(const float4*)&kvb[wv][1][j][4];
      acc[0] += p * v0.x; acc[1] += p * v0.y; acc[2] += p * v0.z; acc[3] += p * v0.w;
      acc[4] += p * v1.x; acc[5] += p * v1.y; acc[6] += p * v1.z; acc[7] += p * v1.w;
    }
#pragma unroll
    for (int d = 0; d < 8; ++d)
      o_out[((size_t)(b * 64 + h * 8 + d) * 128 + row) * 128 + col] = acc[d] * inv;
    __syncthreads();
  }
}

// ------- directional avg pools (reflect+zero pad semantics) + add local -------
__global__ __launch_bounds__(256)
void avgadd_k(const float* __restrict__ o, const float* __restrict__ loc, float* __restrict__ out)
{
  int idx = blockIdx.x * 256 + threadIdx.x;
  if (idx >= 8388608) return;
  int x = idx & 127, y = (idx >> 7) & 127;
  size_t p = (size_t)(idx >> 14);
  const float* op = o + (p << 14);
  float s1 = 0.f, s2 = 0.f;
#pragma unroll
  for (int t = 0; t < 8; ++t) {
    int r = y - 3 + t;
    if (r >= 0 && r <= 128) { int rr = (r == 128) ? 126 : r; s1 += op[rr * 128 + x]; }
    int cc = x - 3 + t;
    if (cc >= 0 && cc <= 128) { int ss = (cc == 128) ? 126 : cc; s2 += op[y * 128 + ss]; }
  }
  out[idx] = 0.125f * (s1 + s2) + loc[idx];
}

// ---------------- depthwise 8x8 conv (pad_out + pad3, zero) + BN ----------------
__global__ __launch_bounds__(256)
void dw_k(const float* __restrict__ in, const float* __restrict__ w,
          const float* __restrict__ g, const float* __restrict__ bb, float* __restrict__ out)
{
  __shared__ float t[23 * 23];
  const int tid = threadIdx.x;
  const int tx = tid & 15, ty = tid >> 4;
  const int x0 = blockIdx.x * 16, y0 = blockIdx.y * 16;
  const int pc = blockIdx.z;
  const int c = pc & 63;
  const float* ip = in + (size_t)pc * 16384;
  for (int e = tid; e < 529; e += 256) {
    int yy = e / 23, xx = e % 23;
    int iy = y0 + yy - 3, ix = x0 + xx - 3;
    t[e] = (iy >= 0 && iy < 128 && ix >= 0 && ix < 128) ? ip[iy * 128 + ix] : 0.f;
  }
  __syncthreads();
  const float* wk = w + c * 64;
  float s = 0.f;
#pragma unroll
  for (int ky = 0; ky < 8; ++ky)
#pragma unroll
    for (int kx = 0; kx < 8; ++kx)
      s += t[(ty + ky) * 23 + tx + kx] * wk[ky * 8 + kx];
  out[(size_t)pc * 16384 + (y0 + ty) * 128 + x0 + tx] = s * (g[c] * BN_SC) + bb[c];
}

// ---------------- final 1x1 conv (w_pw, no bias) ----------------
__global__ __launch_bounds__(256)
void pw_k(const float* __restrict__ in, const float* __restrict__ w, float* __restrict__ out)
{
  int idx = blockIdx.x * 256 + threadIdx.x;
  int b = idx >> 14, px = idx & 16383;
  const float* ip = in + ((size_t)b << 20) + px;
  float v[64];
#pragma unroll
  for (int i = 0; i < 64; ++i) v[i] = ip[(size_t)i << 14];
  float* op = out + ((size_t)b << 20) + px;
  for (int co = 0; co < 64; ++co) {
    const float* wk = w + co * 64;
    float s = 0.f;
#pragma unroll
    for (int i = 0; i < 64; ++i) s += v[i] * wk[i];
    op[(size_t)co << 14] = s;
  }
}

// =======================================================================
extern "C" void kernel_launch(void* const* d_in, const int* in_sizes, int n_in,
                              void* d_out, int out_size, void* d_ws, size_t ws_size,
                              hipStream_t stream)
{
  const float* x      = (const float*)d_in[0];
  const float* w_qkv  = (const float*)d_in[1];
  const float* w_l1   = (const float*)d_in[2];
  const float* g_l1   = (const float*)d_in[3];
  const float* b_l1   = (const float*)d_in[4];
  const float* w_l2   = (const float*)d_in[5];
  const float* g_l2   = (const float*)d_in[6];
  const float* b_l2   = (const float*)d_in[7];
  const float* f_cos  = (const float*)d_in[8];
  const float* f_sin  = (const float*)d_in[9];
  const float* gb_b1  = (const float*)d_in[10];
  const float* gb_b2  = (const float*)d_in[11];
  const float* gb_w   = (const float*)d_in[12];
  const float* w_post = (const float*)d_in[13];
  const float* g_post = (const float*)d_in[14];
  const float* b_post = (const float*)d_in[15];
  const float* w_gc   = (const float*)d_in[16];
  const float* b_gc   = (const float*)d_in[17];
  const float* w_gc1  = (const float*)d_in[18];
  const float* b_gc1  = (const float*)d_in[19];
  const float* w_gc2  = (const float*)d_in[20];
  const float* b_gc2  = (const float*)d_in[21];
  const float* rpb    = (const float*)d_in[22];
  const float* w_dw   = (const float*)d_in[23];
  const float* g_proj = (const float*)d_in[24];
  const float* b_proj = (const float*)d_in[25];
  const float* w_pw   = (const float*)d_in[26];
  const int*   relidx = (const int*)d_in[27];
  float* out = (float*)d_out;

  // Workspace: max byte used = 102,238,208 (round-2-proven footprint).
  char* ws = (char*)d_ws;
  float* R1   = (float*)(ws + 0);                       // 32 MiB
  float* R2   = (float*)(ws + 33554432);                // 32 MiB
  float* R3   = (float*)(ws + 67108864);                // convgc out / out0
  float* C1   = R3;                                     // 16,515,072 B complex (FFT)
  float* C2   = (float*)(ws + 83623936);                // 16,515,072 B (ends 100,139,008)
  float* XC5  = (float*)(ws + 100139008);               // 1,968,128 B (steps 8-9)
  float* RPBT = (float*)(ws + 102107136);               // 131,072 B (ends 102,238,208)
  float* W1S  = (float*)(ws + 67108864);                // prep weights (dead before FFT)
  float* W2S  = (float*)(ws + 67108864 + 147456);
  float* BLS  = (float*)(ws + 67108864 + 163840);

  // 1. fold BN into local-branch weights + rpb gather
  prep_k<<<144, 256, 0, stream>>>(w_l1, g_l1, b_l1, w_l2, g_l2, b_l2, W1S, W2S, BLS);
  rpbprep_k<<<128, 256, 0, stream>>>(rpb, relidx, RPBT);
  // 2. local_pre = bn(conv1x1) + bn(conv3x3)  -> R1
  conv3x3s_k<M_LOCAL, 128, 128, 1><<<dim3(32, 8, 4), 256, 0, stream>>>(x, W1S, W2S, BLS, nullptr, R1);
  // 3. gabor conv (valid, cos||sin + biases)  -> R2 (xc0, 126x126)
  conv3x3s_k<M_GABOR, 128, 126, 0><<<dim3(32, 8, 4), 256, 0, stream>>>(R1, f_cos, f_sin, gb_b1, gb_b2, R2);
  // 4. fft_h + fw-mix, 2 chunks of 256 planes -> R1 (xc1)
  for (int chunk = 0; chunk < 2; ++chunk) {
    int pb = chunk * 256;
    dft_rows_fwd_k<<<256 * 126, 64, 0, stream>>>(R2, C1, pb);
    dft_cols_fwd_mask_k<<<512, 256, 0, stream>>>(C1, C2);
    dft_cols_inv_k<<<512, 256, 0, stream>>>(C2, C1);
    dft_rows_inv_mix_k<<<256 * 126, 128, 0, stream>>>(C1, R2, gb_w, R1, pb);
  }
  // 5. relu6(bn(conv3x3 w_post)) -> R2 (xc2)
  conv3x3s_k<M_BNRELU6, 126, 126, 1><<<dim3(32, 8, 4), 256, 0, stream>>>(R1, w_post, nullptr, g_post, b_post, R2);
  // 6. maxpool 2x2 s1 -> R1 (125^2)
  mp1_k<<<31250, 256, 0, stream>>>(R2, R1);
  // 7. relu(conv3x3 s2 w_gc) -> R3 (62^2)   [tiled]
  convgc_t<<<dim3(16, 8, 2), 256, 0, stream>>>(R1, w_gc, b_gc, R3);
  // 8. maxpool 2x2 s2 -> XC5 (31^2)
  mp2_k<<<1922, 256, 0, stream>>>(R3, XC5);
  // 9. bilinear resize 31 -> 128 -> R1 (xc6)
  resize_k<<<32768, 256, 0, stream>>>(XC5, R1);
  // 10. relu(conv3x3 w_gc1 + b) -> R2 (xc7)
  conv3x3s_k<M_BIASRELU, 128, 128, 1><<<dim3(32, 8, 4), 256, 0, stream>>>(R1, w_gc1, nullptr, b_gc1, nullptr, R2);
  // 11. 1x1 conv w_gc2 + log_softmax -> R1 (local)
  pwlsm_k<<<512, 256, 0, stream>>>(R2, w_gc2, b_gc2, R1);
  // 12. window attention -> R2 (o)   [wave-per-head]
  attn_w_k<<<2048, 256, 0, stream>>>(x, w_qkv, RPBT, R2);
  // 13. ox + oy + local -> R3 (out0)
  avgadd_k<<<32768, 256, 0, stream>>>(R2, R1, R3);
  // 14. depthwise 8x8 + bn -> R2
  dw_k<<<dim3(8, 8, 512), 256, 0, stream>>>(R3, w_dw, g_proj, b_proj, R2);
  // 15. 1x1 conv w_pw -> d_out
  pw_k<<<512, 256, 0, stream>>>(R2, w_pw, out);
  (void)in_sizes; (void)n_in; (void)out_size; (void)ws_size;
}